// Round 2
// baseline (315.868 us; speedup 1.0000x reference)
//
#include <hip/hip_runtime.h>
#include <hip/hip_bf16.h>

typedef unsigned short u16;

#define WPB 8                 // waves per block
#define BLOCK (WPB * 64)
#define NBLOCKS 768

__device__ __forceinline__ float bf2f(u16 u) {
    union { unsigned int i; float f; } v;
    v.i = ((unsigned int)u) << 16;
    return v.f;
}
__device__ __forceinline__ u16 f2bf(float f) {   // RNE
    union { float f; unsigned int u; } v;
    v.f = f;
    unsigned int r = v.u + 0x7fff + ((v.u >> 16) & 1);
    return (u16)(r >> 16);
}

// Fused SPHeroConv (all-f32 I/O):
//   Phase A (lane = c): acc[s][c] = sum_edges sph[s] * feat[c]
//   Phase B (lane = f): out[o][f] = bias[f] + sum_{s,c} acc[s][c] * K[s][c][f]
__global__ __launch_bounds__(BLOCK)
void sphconv_fused(const float* __restrict__ feats,    // [N_IN, 64]
                   const float* __restrict__ in_pos,   // [N_IN, 3]
                   const float* __restrict__ out_pos,  // [N_OUT, 3]
                   const float* __restrict__ extents,  // [1]
                   const float* __restrict__ kmat,     // [4,64,64]
                   const float* __restrict__ bias,     // [64]
                   const int* __restrict__ nidx,       // [E]
                   const int* __restrict__ rsplits,    // [N_OUT+1]
                   float* __restrict__ out,            // [N_OUT,64]
                   int n_out)
{
    // K staged as bf16 [c][f][s] (32 KB): Phase B reads ushort4 (8B) per (c,f).
    __shared__ u16 Ktb[64 * 64 * 4];
    // per-wave acc scratch: [wave][pair-slot][c][s] f32 (16 KB)
    __shared__ __align__(16) float accL[WPB][2][64][4];

    // ---- stage kernel matrix: global f32 [s][c][f] -> LDS bf16 [c][f][s] ----
    for (int i = threadIdx.x; i < 4 * 64 * 64; i += BLOCK) {
        int s = i >> 12;
        int c = (i >> 6) & 63;
        int f = i & 63;
        Ktb[(((c << 6) | f) << 2) | s] = f2bf(kmat[i]);
    }
    __syncthreads();

    const int wave = threadIdx.x >> 6;
    const int lane = threadIdx.x & 63;
    const int gw   = blockIdx.x * WPB + wave;
    const int nw   = gridDim.x * WPB;
    const int npairs = (n_out + 1) >> 1;
    const int iters  = (npairs + nw - 1) / nw;   // uniform across the whole grid

    const float inv_ext = __fdividef(1.0f, extents[0]);

    for (int it = 0; it < iters; ++it) {
        const int pair  = gw + it * nw;
        const bool valid = pair < npairs;
        const int o0 = pair << 1;

        // ---------------- Phase A: edge gather + spherical weighting ----------------
        if (valid) {
            for (int po = 0; po < 2; ++po) {
                const int o = o0 + po;
                float a0 = 0.f, a1 = 0.f, a2 = 0.f, a3 = 0.f;
                if (o < n_out) {
                    const float qx = out_pos[o * 3 + 0];
                    const float qy = out_pos[o * 3 + 1];
                    const float qz = out_pos[o * 3 + 2];
                    const int e0 = rsplits[o];
                    const int e1 = rsplits[o + 1];
                    for (int e = e0; e < e1; ++e) {
                        const int idx = nidx[e];                       // wave-uniform
                        const float dx = in_pos[idx * 3 + 0] - qx;
                        const float dy = in_pos[idx * 3 + 1] - qy;
                        const float dz = in_pos[idx * 3 + 2] - qz;
                        const float rp2 = dx * dx + dy * dy;
                        const float r2  = rp2 + dz * dz;
                        const float rs  = fmaxf(sqrtf(r2), 1e-10f);
                        const float rp  = fmaxf(sqrtf(rp2), 1e-10f);
                        const float inv_r  = __fdividef(1.0f, rs);
                        const float inv_rp = __fdividef(1.0f, rp);
                        const float rn  = rs * inv_ext;                // r_normalized
                        const float cph = dz * inv_r;                  // cos_phi
                        const float sth = dy * inv_rp;                 // sin_theta
                        const float cth = dx * inv_rp;                 // cos_theta
                        const float fe  = feats[(idx << 6) | lane];    // coalesced gather
                        a0 = fmaf(rn,  fe, a0);
                        a1 = fmaf(cph, fe, a1);
                        a2 = fmaf(sth, fe, a2);
                        a3 = fmaf(cth, fe, a3);
                    }
                }
                float4* ap = (float4*)&accL[wave][po][lane][0];
                *ap = make_float4(a0, a1, a2, a3);   // ds_write_b128
            }
        }
        __syncthreads();

        // ---------------- Phase B: 256 x 64 matvec per output (pair shares K reads) ----------------
        if (valid) {
            float ob0 = 0.f, ob1 = 0.f;
            const u16* kt = &Ktb[lane << 2];
            #pragma unroll 8
            for (int c = 0; c < 64; ++c) {
                const ushort4 k4 = *(const ushort4*)&kt[c << 8];       // ds_read_b64, dense
                const float k0 = bf2f(k4.x), k1 = bf2f(k4.y);
                const float k2 = bf2f(k4.z), k3 = bf2f(k4.w);
                const float4 aA = *(const float4*)&accL[wave][0][c][0]; // b128 broadcast
                const float4 aB = *(const float4*)&accL[wave][1][c][0];
                ob0 = fmaf(aA.x, k0, ob0); ob0 = fmaf(aA.y, k1, ob0);
                ob0 = fmaf(aA.z, k2, ob0); ob0 = fmaf(aA.w, k3, ob0);
                ob1 = fmaf(aB.x, k0, ob1); ob1 = fmaf(aB.y, k1, ob1);
                ob1 = fmaf(aB.z, k2, ob1); ob1 = fmaf(aB.w, k3, ob1);
            }
            const float bv = bias[lane];
            out[(o0 << 6) | lane] = ob0 + bv;
            if (o0 + 1 < n_out)
                out[((o0 + 1) << 6) | lane] = ob1 + bv;
        }
        __syncthreads();   // protect accL against next iteration's Phase A writes
    }
}

extern "C" void kernel_launch(void* const* d_in, const int* in_sizes, int n_in,
                              void* d_out, int out_size, void* d_ws, size_t ws_size,
                              hipStream_t stream) {
    const float* feats   = (const float*)d_in[0];
    const float* in_pos  = (const float*)d_in[1];
    const float* out_pos = (const float*)d_in[2];
    const float* extents = (const float*)d_in[3];
    const float* kmat    = (const float*)d_in[4];
    const float* bias    = (const float*)d_in[5];
    const int*   nidx    = (const int*)d_in[6];
    const int*   rsplits = (const int*)d_in[7];
    const int n_out = in_sizes[7] - 1;   // neighbors_row_splits has N_OUT+1 entries

    sphconv_fused<<<NBLOCKS, BLOCK, 0, stream>>>(
        feats, in_pos, out_pos, extents, kmat, bias, nidx, rsplits,
        (float*)d_out, n_out);
}

// Round 3
// 128.345 us; speedup vs baseline: 2.4611x; 2.4611x over previous
//
#include <hip/hip_runtime.h>

typedef unsigned short u16;
typedef __attribute__((ext_vector_type(8))) short bf16x8;   // MFMA A/B frag: 8 bf16
typedef __attribute__((ext_vector_type(4))) float f32x4;    // MFMA C/D frag

#define WPB   4              // waves per block; one 16-output tile per wave
#define BLOCK (WPB * 64)

__device__ __forceinline__ u16 f2bf(float f) {   // RNE f32 -> bf16
    union { float f; unsigned u; } v; v.f = f;
    unsigned r = v.u + 0x7fff + ((v.u >> 16) & 1);
    return (u16)(r >> 16);
}

// One wave handles 16 outputs (one MFMA M-tile):
//   A1: 256 edges spread over lanes (4/lane) -> sph[4] + idx staged in LDS
//   A2: lane(m=lane&15, quad=lane>>4) accumulates acc[kstep][j] (A-frag layout)
//       acc_k(m) = sum_t sph[m][t][s(k)] * feats[idx[m][t]][c(k)],  k = s*64+c
//   B : 4 n-tiles x 8 k-steps of mfma_f32_16x16x32_bf16 against LDS-staged
//       K B-fragments;  out[o][f] = D + bias[f]
__global__ __launch_bounds__(BLOCK, 3)
void sphconv_mfma(const float* __restrict__ feats,    // [N_IN, 64]
                  const float* __restrict__ in_pos,   // [N_IN, 3]
                  const float* __restrict__ out_pos,  // [N_OUT, 3]
                  const float* __restrict__ extents,  // [1]
                  const float* __restrict__ kmat,     // [4,64,64] = [k=256][f=64]
                  const float* __restrict__ bias,     // [64]
                  const int* __restrict__ nidx,       // [E]
                  const int* __restrict__ rsplits,    // [N_OUT+1]
                  float* __restrict__ out,            // [N_OUT,64]
                  int n_out, int ntiles)
{
    // K as ready-made B-fragments, bf16: [ntile][kstep][lane][j]  (32 KB)
    __shared__ u16 KB[4 * 8 * 64 * 8];
    // wave-private tile scratch
    __shared__ int   idxL[WPB][16][16];      // [wave][t][m]       (4 KB)
    __shared__ float sphL[WPB][16][16][4];   // [wave][t][m][s]    (16 KB)

    const int tid  = threadIdx.x;
    const int wave = tid >> 6;
    const int lane = tid & 63;

    // ---- stage K (coalesced global read, scattered LDS u16 write; once) ----
    for (int i = tid; i < 16384; i += BLOCK) {
        const int n = i & 63, k = i >> 6;               // kmat flat = [k][n]
        const int kstep = k >> 5, quad = (k >> 3) & 3, j = k & 7;
        const int ntile = n >> 4, lanep = (quad << 4) | (n & 15);
        KB[((((ntile << 3) | kstep) << 6) | lanep) * 8 + j] = f2bf(kmat[i]);
    }
    __syncthreads();   // the only block-wide barrier

    const int tile = blockIdx.x * WPB + wave;
    if (tile >= ntiles) return;

    const float inv_ext = __fdividef(1.0f, extents[0]);

    // ---------------- Phase A1: per-edge spherical basis (4 edges/lane) ----------------
    #pragma unroll
    for (int u = 0; u < 4; ++u) {
        const int slot = (u << 6) | lane;      // 0..255 within tile
        const int m = slot >> 4, t = slot & 15;
        const int o = (tile << 4) | m;
        float rn = 0.f, cph = 0.f, sth = 0.f, cth = 0.f;
        int idx = 0;
        if (o < n_out) {
            const int e0 = rsplits[o], e1 = rsplits[o + 1];
            const int e = e0 + t;
            if (e < e1) {
                idx = nidx[e];
                const float dx = in_pos[idx * 3 + 0] - out_pos[o * 3 + 0];
                const float dy = in_pos[idx * 3 + 1] - out_pos[o * 3 + 1];
                const float dz = in_pos[idx * 3 + 2] - out_pos[o * 3 + 2];
                const float rp2 = dx * dx + dy * dy;
                const float r2  = rp2 + dz * dz;
                const float rs  = fmaxf(sqrtf(r2), 1e-10f);
                const float rp  = fmaxf(sqrtf(rp2), 1e-10f);
                const float ir  = __fdividef(1.0f, rs);
                const float irp = __fdividef(1.0f, rp);
                rn  = rs * inv_ext;
                cph = dz * ir;
                sth = dy * irp;
                cth = dx * irp;
            }
        }
        idxL[wave][t][m] = idx;
        f32x4 sv; sv.x = rn; sv.y = cph; sv.z = sth; sv.w = cth;
        *(f32x4*)&sphL[wave][t][m][0] = sv;     // ds_write_b128
    }
    __builtin_amdgcn_wave_barrier();   // order A1 LDS writes vs A2 cross-lane reads

    // ---------------- Phase A2: accumulate A-fragments in registers ----------------
    const int m    = lane & 15;
    const int quad = lane >> 4;
    float acc[8][8];
    #pragma unroll
    for (int ks = 0; ks < 8; ++ks)
        #pragma unroll
        for (int j = 0; j < 8; ++j) acc[ks][j] = 0.f;

    #pragma unroll 4
    for (int t = 0; t < 16; ++t) {
        const int   idx = idxL[wave][t][m];
        const f32x4 sv  = *(const f32x4*)&sphL[wave][t][m][0];
        const float* fr = feats + (idx << 6) + (quad << 3);
        const float4 lo0 = *(const float4*)(fr +  0);
        const float4 lo1 = *(const float4*)(fr +  4);
        const float4 hi0 = *(const float4*)(fr + 32);
        const float4 hi1 = *(const float4*)(fr + 36);
        #pragma unroll
        for (int s = 0; s < 4; ++s) {
            const float w = sv[s];
            float* aL = acc[2 * s];          // c = quad*8 + j
            float* aH = acc[2 * s + 1];      // c = 32 + quad*8 + j
            aL[0] = fmaf(w, lo0.x, aL[0]); aL[1] = fmaf(w, lo0.y, aL[1]);
            aL[2] = fmaf(w, lo0.z, aL[2]); aL[3] = fmaf(w, lo0.w, aL[3]);
            aL[4] = fmaf(w, lo1.x, aL[4]); aL[5] = fmaf(w, lo1.y, aL[5]);
            aL[6] = fmaf(w, lo1.z, aL[6]); aL[7] = fmaf(w, lo1.w, aL[7]);
            aH[0] = fmaf(w, hi0.x, aH[0]); aH[1] = fmaf(w, hi0.y, aH[1]);
            aH[2] = fmaf(w, hi0.z, aH[2]); aH[3] = fmaf(w, hi0.w, aH[3]);
            aH[4] = fmaf(w, hi1.x, aH[4]); aH[5] = fmaf(w, hi1.y, aH[5]);
            aH[6] = fmaf(w, hi1.z, aH[6]); aH[7] = fmaf(w, hi1.w, aH[7]);
        }
    }

    // ---- pack acc -> bf16 A-fragments ----
    bf16x8 afr[8];
    #pragma unroll
    for (int ks = 0; ks < 8; ++ks) {
        union { u16 h[8]; bf16x8 v; } p;
        #pragma unroll
        for (int j = 0; j < 8; ++j) p.h[j] = f2bf(acc[ks][j]);
        afr[ks] = p.v;
    }

    // ---------------- Phase B: 4 n-tiles x 8 k-steps of MFMA ----------------
    const int obase = tile << 4;
    #pragma unroll
    for (int nt = 0; nt < 4; ++nt) {
        f32x4 C = {0.f, 0.f, 0.f, 0.f};
        const u16* kb = &KB[((nt << 3) << 6) * 8 + lane * 8];
        #pragma unroll
        for (int ks = 0; ks < 8; ++ks) {
            const bf16x8 b = *(const bf16x8*)(kb + (ks << 6) * 8);  // ds_read_b128
            C = __builtin_amdgcn_mfma_f32_16x16x32_bf16(afr[ks], b, C, 0, 0, 0);
        }
        const int f  = (nt << 4) | m;          // n = lane&15
        const float bv = bias[f];
        #pragma unroll
        for (int r = 0; r < 4; ++r) {
            const int oo = obase + (quad << 2) + r;   // m = quad*4 + reg
            if (oo < n_out) out[(oo << 6) | f] = C[r] + bv;
        }
    }
}

extern "C" void kernel_launch(void* const* d_in, const int* in_sizes, int n_in,
                              void* d_out, int out_size, void* d_ws, size_t ws_size,
                              hipStream_t stream) {
    const float* feats   = (const float*)d_in[0];
    const float* in_pos  = (const float*)d_in[1];
    const float* out_pos = (const float*)d_in[2];
    const float* extents = (const float*)d_in[3];
    const float* kmat    = (const float*)d_in[4];
    const float* bias    = (const float*)d_in[5];
    const int*   nidx    = (const int*)d_in[6];
    const int*   rsplits = (const int*)d_in[7];
    const int n_out  = in_sizes[7] - 1;
    const int ntiles = (n_out + 15) >> 4;
    const int grid   = (ntiles + WPB - 1) / WPB;

    sphconv_mfma<<<grid, BLOCK, 0, stream>>>(
        feats, in_pos, out_pos, extents, kmat, bias, nidx, rsplits,
        (float*)d_out, n_out, ntiles);
}